// Round 13
// baseline (390.369 us; speedup 1.0000x reference)
//
#include <hip/hip_runtime.h>
#include <math.h>

#define B_ 64
#define P_ 8732
#define M_ 16
#define C_ 81
#define THRESH 0.5f
#define EPS_ 1e-7f

#define CE_BLOCKS 2048                          // 256 CUs * 8 blocks/CU (no LDS)

// ---------------------------------------------------------------------------
// Kernel 1: per-batch prior assignment (R10-verified two-pass 256-thread
// structure) + n_pos count + counter zeroing. 64 blocks, ~12-15 us.
// ---------------------------------------------------------------------------
__global__ __launch_bounds__(256) void assign_kernel(
    const float* __restrict__ boxes,    // [B,M,4] corner
    const int*   __restrict__ labels,   // [B,M]
    const float* __restrict__ priors,   // [P,4] cxcy
    int*         __restrict__ tcls,     // [B*P]
    int*         __restrict__ n_pos,    // [B]
    int*         __restrict__ ctrs)     // [2]
{
    __shared__ float s_bx[M_][4];
    __shared__ float s_barea[M_];
    __shared__ int   s_lab[M_];
    __shared__ float s_wv4[M_][4];
    __shared__ int   s_wp4[M_][4];
    __shared__ int   s_tp[M_];
    __shared__ int   s_tn;
    __shared__ int   s_cnt[4];

    const int b    = blockIdx.x;
    const int tid  = threadIdx.x;
    const int lane = tid & 63;
    const int wv   = tid >> 6;                  // 4 waves

    if (b == 0 && tid < 2) ctrs[tid] = 0;       // done-counter for topk finalize

    if (tid < M_*4) ((float*)s_bx)[tid] = boxes[b*M_*4 + tid];
    if (tid < M_)   s_lab[tid] = labels[b*M_ + tid];
    __syncthreads();
    if (tid < M_)
        s_barea[tid] = (s_bx[tid][2]-s_bx[tid][0])*(s_bx[tid][3]-s_bx[tid][1]);
    __syncthreads();

    const float4* pri4 = (const float4*)priors;

    // ---- pass 1: per-object best prior (argmax over p, first-p wins) ----
    float bestv[M_]; int bestp[M_];
    #pragma unroll
    for (int m = 0; m < M_; ++m) { bestv[m] = -1.0f; bestp[m] = 0x7fffffff; }

    for (int p = tid; p < P_; p += 256) {
        float4 pc = pri4[p];
        float px1 = pc.x - pc.z*0.5f, py1 = pc.y - pc.w*0.5f;
        float px2 = pc.x + pc.z*0.5f, py2 = pc.y + pc.w*0.5f;
        float parea = (px2-px1)*(py2-py1);
        #pragma unroll
        for (int m = 0; m < M_; ++m) {
            float ix1 = fmaxf(s_bx[m][0], px1);
            float iy1 = fmaxf(s_bx[m][1], py1);
            float ix2 = fminf(s_bx[m][2], px2);
            float iy2 = fminf(s_bx[m][3], py2);
            float iw = fmaxf(ix2-ix1, 0.0f);
            float ih = fmaxf(iy2-iy1, 0.0f);
            float inter = iw*ih;
            float iou = inter / (s_barea[m] + parea - inter); // jaccard: no eps
            if (iou > bestv[m]) { bestv[m] = iou; bestp[m] = p; } // first p wins
        }
    }

    #pragma unroll
    for (int m = 0; m < M_; ++m) {
        float v = bestv[m]; int p = bestp[m];
        #pragma unroll
        for (int o = 32; o; o >>= 1) {
            float v2 = __shfl_xor(v, o);
            int   p2 = __shfl_xor(p, o);
            if (v2 > v || (v2 == v && p2 < p)) { v = v2; p = p2; }
        }
        if (lane == 0) { s_wv4[m][wv] = v; s_wp4[m][wv] = p; }
    }
    __syncthreads();

    // ---- serial: final reduce + faithful filtered-index override table ----
    if (tid == 0) {
        int cnt = 0;
        for (int m = 0; m < M_; ++m) {
            float v = s_wv4[m][0]; int p = s_wp4[m][0];
            #pragma unroll
            for (int w = 1; w < 4; ++w) {
                float v2 = s_wv4[m][w]; int p2 = s_wp4[m][w];
                if (v2 > v || (v2 == v && p2 < p)) { v = v2; p = p2; }
            }
            if (v > 0.0f) { s_tp[cnt] = p; cnt++; }  // entry e -> obj idx e
        }
        s_tn = cnt;
    }
    __syncthreads();

    const int tn = s_tn;

    // ---- pass 2: per-prior best (bitwise-identical recompute) + override ----
    int cpos = 0;
    for (int p = tid; p < P_; p += 256) {
        float4 pc = pri4[p];
        float px1 = pc.x - pc.z*0.5f, py1 = pc.y - pc.w*0.5f;
        float px2 = pc.x + pc.z*0.5f, py2 = pc.y + pc.w*0.5f;
        float parea = (px2-px1)*(py2-py1);
        float bv = -1.0f; int bm = 0;
        #pragma unroll
        for (int m = 0; m < M_; ++m) {
            float ix1 = fmaxf(s_bx[m][0], px1);
            float iy1 = fmaxf(s_bx[m][1], py1);
            float ix2 = fminf(s_bx[m][2], px2);
            float iy2 = fminf(s_bx[m][3], py2);
            float iw = fmaxf(ix2-ix1, 0.0f);
            float ih = fmaxf(iy2-iy1, 0.0f);
            float inter = iw*ih;
            float iou = inter / (s_barea[m] + parea - inter);
            if (iou > bv) { bv = iou; bm = m; }       // first-max (m asc)
        }
        int ovr = -1;
        for (int e = 0; e < tn; ++e)
            if (s_tp[e] == p) ovr = e;                // last valid m wins
        int tc = (ovr >= 0) ? s_lab[ovr]              // ovl forced to 1.0
                            : ((bv < THRESH) ? 0 : s_lab[bm]);
        tcls[(size_t)b*P_ + p] = tc;
        cpos += (tc > 0);
    }

    #pragma unroll
    for (int o = 32; o; o >>= 1) cpos += __shfl_xor(cpos, o);
    if (lane == 0) s_cnt[wv] = cpos;
    __syncthreads();
    if (tid == 0) {
        int t = 0;
        #pragma unroll
        for (int w = 0; w < 4; ++w) t += s_cnt[w];
        n_pos[b] = t;
    }
}

// ---------------------------------------------------------------------------
// Kernel 2: CE over C=81 + positive-gated DIoU self-loss. R0-VERIFIED
// structure: no LDS in the hot loop, no barriers, 16 lanes/row with 6 row
// elements in VGPRs, 4-step shfl group reductions, full occupancy
// (8 blocks/CU, 32 waves/CU). Latency-bound stream hidden by raw TLP.
// ---------------------------------------------------------------------------
__global__ __launch_bounds__(256) void ce_loc_kernel(
    const float* __restrict__ scores,   // [B,P,C]
    const float* __restrict__ locs,     // [B,P,4]
    const int*   __restrict__ tcls,     // [B,P]
    float*       __restrict__ conf_neg, // [B,P]
    float*       __restrict__ blk_pos,  // [CE_BLOCKS]
    float*       __restrict__ blk_loc)  // [CE_BLOCKS]
{
    const int tid  = threadIdx.x;
    const int lane = tid & 63;
    const int j    = lane & 15;         // lane within row-group
    const int g    = lane >> 4;         // row-group within wave (0..3)
    const int wv   = tid >> 6;
    const int gwave = blockIdx.x * 4 + wv;
    const int ngrp  = CE_BLOCKS * 4;    // total waves
    const int NG = (B_ * P_) / 4;       // row-groups of 4 (R % 4 == 0)

    __shared__ float s_red[4][2];

    float p_acc = 0.f, l_acc = 0.f;

    for (int grp = gwave; grp < NG; grp += ngrp) {
        const int r = grp * 4 + g;
        const float* row = scores + (size_t)r * C_;

        float x[6];
        #pragma unroll
        for (int k = 0; k < 5; ++k) x[k] = row[16*k + j];
        x[5] = (j == 0) ? row[80] : -INFINITY;

        float mx = fmaxf(fmaxf(fmaxf(x[0], x[1]), fmaxf(x[2], x[3])),
                         fmaxf(x[4], x[5]));
        #pragma unroll
        for (int o = 1; o < 16; o <<= 1) mx = fmaxf(mx, __shfl_xor(mx, o));

        const int t = tcls[r];
        float e = 0.f, st = 0.f;
        #pragma unroll
        for (int k = 0; k < 6; ++k) {
            e += __expf(x[k] - mx);            // exp(-inf)=0 for pad
            const int idx = 16*k + j;
            if (idx == t) st = x[k];           // exactly one lane matches
        }
        #pragma unroll
        for (int o = 1; o < 16; o <<= 1) {
            e  += __shfl_xor(e, o);
            st += __shfl_xor(st, o);
        }

        if (j == 0) {
            float conf = mx + __logf(e) - st;  // -log_softmax[t]
            if (t > 0) {
                conf_neg[r] = 0.f;
                p_acc += conf;
                // DIoU(box, box): inter_diag == 0; enclosing box == box
                float4 bx = ((const float4*)locs)[r];
                float w = bx.z - bx.x, h = bx.w - bx.y;
                float iw = fmaxf(w, 0.f), ih = fmaxf(h, 0.f);
                float inter = iw * ih;
                float area  = w * h;
                float iou   = inter / (area + area - inter + EPS_);
                float diou  = fminf(fmaxf(iou, -1.f), 1.f);
                l_acc += 1.f - diou;
            } else {
                conf_neg[r] = fmaxf(conf, 0.f); // order-monotonic float bits
            }
        }
    }

    #pragma unroll
    for (int o = 32; o; o >>= 1) {
        p_acc += __shfl_xor(p_acc, o);
        l_acc += __shfl_xor(l_acc, o);
    }
    if (lane == 0) { s_red[wv][0] = p_acc; s_red[wv][1] = l_acc; }
    __syncthreads();
    if (tid == 0) {
        blk_pos[blockIdx.x] = s_red[0][0] + s_red[1][0] + s_red[2][0] + s_red[3][0];
        blk_loc[blockIdx.x] = s_red[0][1] + s_red[1][1] + s_red[2][1] + s_red[3][1];
    }
}

// ---------------------------------------------------------------------------
// Kernel 3: select-only top-k (k = 3*n_pos[b]) per batch: float4 conf_neg
// load, 256-bin radix select (R2/R5-verified core), tie-exact sum, plus
// R5-verified last-block scalar finalize (kills the 4th kernel).
// ---------------------------------------------------------------------------
__global__ __launch_bounds__(1024) void topk_kernel(
    const float* __restrict__ conf_neg, // [B,P]
    const int*   __restrict__ n_pos,    // [B] (from assign, prior dispatch)
    const float* __restrict__ blk_pos,  // [CE_BLOCKS] (prior dispatch)
    const float* __restrict__ blk_loc,  // [CE_BLOCKS]
    float*       __restrict__ hard,     // [B]
    int*         __restrict__ ctrs,     // [1]=done
    float*       __restrict__ out)      // [1]
{
    const int b = blockIdx.x;
    const int tid = threadIdx.x;
    const int lane = tid & 63;
    const int wv = tid >> 6;

    __shared__ float s_v[P_];           // 34928 B
    __shared__ int   s_hist[16][256];   // 16384 B
    __shared__ int   s_cg[257];
    __shared__ int   s_sel;
    __shared__ int   s_t[16];
    __shared__ float s_f[16];
    __shared__ int   s_last;
    __shared__ double sd[16][4];

    const float4* cn4 = (const float4*)(conf_neg + (size_t)b * P_);
    for (int i = tid; i < P_/4; i += 1024) ((float4*)s_v)[i] = cn4[i];

    int k = 3 * n_pos[b];
    if (k > P_) k = P_;
    __syncthreads();                    // s_v ready (k is uniform)

    float hsum = 0.f;                   // tid 0's value is the one that counts
    if (k > 0) {                        // block-uniform branch
        const unsigned masks[4]  = {0u, 0xFF800000u, 0xFFFF8000u, 0xFFFFFF80u};
        const int      shifts[4] = {23, 15, 7, 0};

        unsigned prefix = 0u;
        int k_rem = k;

        for (int rd = 0; rd < 4; ++rd) {
            const unsigned hm = masks[rd];
            const int sh = shifts[rd];

            ((int*)s_hist)[tid] = 0;
            ((int*)s_hist)[tid + 1024] = 0;
            ((int*)s_hist)[tid + 2048] = 0;
            ((int*)s_hist)[tid + 3072] = 0;
            __syncthreads();

            for (int i = tid; i < P_; i += 1024) {
                unsigned u = __float_as_uint(s_v[i]);
                if ((u & hm) == prefix)
                    atomicAdd(&s_hist[wv][(u >> sh) & 0xFF], 1);
            }
            __syncthreads();

            if (wv == 0) {
                int carry = 0;
                for (int cbin = 3; cbin >= 0; --cbin) {
                    int bin = cbin * 64 + lane;
                    int tot = 0;
                    #pragma unroll
                    for (int w = 0; w < 16; ++w) tot += s_hist[w][bin];
                    #pragma unroll
                    for (int o = 1; o < 64; o <<= 1) {
                        int v = __shfl_down(tot, o);
                        if (lane + o < 64) tot += v;
                    }
                    int cg = tot + carry;
                    s_cg[bin] = cg;
                    carry = __shfl(cg, 0);
                }
                if (lane == 0) s_cg[256] = 0;
            }
            __syncthreads();

            if (tid < 256) {
                if (s_cg[tid] >= k_rem && s_cg[tid + 1] < k_rem) s_sel = tid;
            }
            __syncthreads();

            const int bsel = s_sel;
            k_rem -= s_cg[bsel + 1];
            prefix |= (unsigned)bsel << sh;
            __syncthreads();
        }

        const float tval = __uint_as_float(prefix);   // exact k-th largest

        float sum = 0.f; int cgt = 0;
        for (int i = tid; i < P_; i += 1024) {
            float v = s_v[i];
            if (v > tval) { sum += v; cgt++; }
        }
        #pragma unroll
        for (int o = 32; o; o >>= 1) { sum += __shfl_xor(sum, o); cgt += __shfl_xor(cgt, o); }
        if (lane == 0) { s_f[wv] = sum; s_t[wv] = cgt; }
        __syncthreads();
        if (tid == 0) {
            float ssum = 0.f; int cc = 0;
            #pragma unroll
            for (int w = 0; w < 16; ++w) { ssum += s_f[w]; cc += s_t[w]; }
            hsum = ssum + (float)(k - cc) * tval;
        }
    }

    // ---- publish + last-block finalize (all blocks reach here) ----
    if (tid == 0) {
        atomicExch(&hard[b], hsum);     // coherent-point store
        __threadfence();                // release before counter bump
        s_last = (atomicAdd(&ctrs[1], 1) == B_ - 1) ? 1 : 0;
    }
    __syncthreads();

    if (s_last) {
        __threadfence();                // acquire side
        double p = 0.0, l = 0.0, h = 0.0, np = 0.0;
        for (int i = tid; i < CE_BLOCKS; i += 1024) { p += blk_pos[i]; l += blk_loc[i]; }
        if (tid < B_) {
            h  = (double)atomicAdd(&hard[tid], 0.0f);   // same-dispatch data
            np = (double)n_pos[tid];                    // prior dispatch: plain read
        }
        #pragma unroll
        for (int o = 32; o; o >>= 1) {
            p += __shfl_xor(p, o); l += __shfl_xor(l, o);
            h += __shfl_xor(h, o); np += __shfl_xor(np, o);
        }
        if (lane == 0) { sd[wv][0] = p; sd[wv][1] = l; sd[wv][2] = h; sd[wv][3] = np; }
        __syncthreads();
        if (tid == 0) {
            double tp = 0, tl = 0, th = 0, tn = 0;
            #pragma unroll
            for (int w = 0; w < 16; ++w) { tp += sd[w][0]; tl += sd[w][1]; th += sd[w][2]; tn += sd[w][3]; }
            double conf_loss = (th + tp) / tn;
            double loc_loss  = tl / fmax(tn, 1.0);
            out[0] = (float)(conf_loss + 1.0 * loc_loss);
        }
    }
}

extern "C" void kernel_launch(void* const* d_in, const int* in_sizes, int n_in,
                              void* d_out, int out_size, void* d_ws, size_t ws_size,
                              hipStream_t stream) {
    const float* predicted_locs   = (const float*)d_in[0];
    const float* predicted_scores = (const float*)d_in[1];
    const float* boxes            = (const float*)d_in[2];
    const int*   labels           = (const int*)d_in[3];
    const float* priors           = (const float*)d_in[4];
    float* out = (float*)d_out;

    char* ws = (char*)d_ws;
    size_t off = 0;
    int*   tcls     = (int*)(ws + off);   off += sizeof(int)   * (size_t)B_ * P_;
    float* conf_neg = (float*)(ws + off); off += sizeof(float) * (size_t)B_ * P_;
    float* blk_pos  = (float*)(ws + off); off += sizeof(float) * CE_BLOCKS;
    float* blk_loc  = (float*)(ws + off); off += sizeof(float) * CE_BLOCKS;
    int*   n_pos    = (int*)(ws + off);   off += sizeof(int)   * B_;
    float* hard     = (float*)(ws + off); off += sizeof(float) * B_;
    int*   ctrs     = (int*)(ws + off);   off += sizeof(int)   * 4;

    assign_kernel<<<B_, 256, 0, stream>>>(boxes, labels, priors,
                                          tcls, n_pos, ctrs);
    ce_loc_kernel<<<CE_BLOCKS, 256, 0, stream>>>(predicted_scores, predicted_locs,
                                                 tcls, conf_neg, blk_pos, blk_loc);
    topk_kernel<<<B_, 1024, 0, stream>>>(conf_neg, n_pos, blk_pos, blk_loc,
                                         hard, ctrs, out);
}